// Round 4
// baseline (408.668 us; speedup 1.0000x reference)
//
#include <hip/hip_runtime.h>
#include <cstdint>

typedef unsigned short u16;
typedef short bf16x8 __attribute__((ext_vector_type(8)));
typedef float floatx4 __attribute__((ext_vector_type(4)));

// Problem dims
#define BB 2048
#define UU 1024
#define HUx 256
// d_out element offsets: main_h, main_c, hyper_out, hyper_c
#define O_H  0
#define O_C  (BB*UU)
#define O_HO (2*BB*UU)
#define O_HC (2*BB*UU + BB*HUx)

__device__ __forceinline__ float bf2f(u16 u) {
    union { uint32_t i; float f; } v; v.i = ((uint32_t)u) << 16; return v.f;
}
__device__ __forceinline__ u16 f2bf(float f) {
    union { float f; uint32_t i; } v; v.f = f;
    uint32_t r = v.i + 0x7fffu + ((v.i >> 16) & 1u);
    return (u16)(r >> 16);
}
__device__ __forceinline__ float sigf(float x) { return 1.f / (1.f + expf(-x)); }
__device__ __forceinline__ float ldmix(const void* p, size_t i, int isbf) {
    return isbf ? bf2f(((const u16*)p)[i]) : ((const float*)p)[i];
}

// ---------------- dtype detection (1 = bf16, 0 = fp32) ----------------
__global__ void detect_dtype(const u16* __restrict__ raw, int* __restrict__ flag) {
    u16 u = raw[2 * threadIdx.x];
    int e = (u >> 7) & 0xFF;
    unsigned long long m = __ballot(e >= 100 && e <= 134);
    if (threadIdx.x == 0) *flag = (__popcll(m) >= 32) ? 1 : 0;
}

// ---------------- input -> bf16 hi (+ optional lo residual) planes ----------------
__global__ void cvt_in2(const void* __restrict__ src, u16* __restrict__ hi,
                        u16* __restrict__ lo, int n8, const int* __restrict__ flag) {
    int i = blockIdx.x * 256 + threadIdx.x;
    if (i >= n8) return;
    if (*flag) {
        ((bf16x8*)hi)[i] = ((const bf16x8*)src)[i];
        if (lo) { bf16x8 z = {}; ((bf16x8*)lo)[i] = z; }
    } else {
        const float* s = (const float*)src + (size_t)i * 8;
        #pragma unroll
        for (int j = 0; j < 8; j++) {
            float v = s[j];
            u16 h = f2bf(v);
            hi[(size_t)i * 8 + j] = h;
            if (lo) lo[(size_t)i * 8 + j] = f2bf(v - bf2f(h));
        }
    }
}

// ---------------- transpose(+convert) hi (+ optional lo): out[c*ostride+ocol+r]=in[r*C+c] ----------------
__global__ void transpose_cvt2(const void* __restrict__ in, u16* __restrict__ out_hi,
                               u16* __restrict__ out_lo, int R, int C, int ostride, int ocol,
                               const int* __restrict__ flag) {
    __shared__ u16 th[32][33];
    __shared__ u16 tl[32][33];
    int isbf = *flag;
    int c0 = blockIdx.x * 32, r0 = blockIdx.y * 32;
    int tx = threadIdx.x, ty = threadIdx.y;  // block (32,8)
    #pragma unroll
    for (int i = 0; i < 32; i += 8) {
        size_t idx = (size_t)(r0 + ty + i) * C + c0 + tx;
        u16 h; u16 l = 0;
        if (isbf) {
            h = ((const u16*)in)[idx];
        } else {
            float v = ((const float*)in)[idx];
            h = f2bf(v);
            l = f2bf(v - bf2f(h));
        }
        th[ty + i][tx] = h;
        tl[ty + i][tx] = l;
    }
    __syncthreads();
    #pragma unroll
    for (int i = 0; i < 32; i += 8) {
        size_t o = (size_t)(c0 + ty + i) * ostride + ocol + r0 + tx;
        out_hi[o] = th[tx][ty + i];
        if (out_lo) out_lo[o] = tl[tx][ty + i];
    }
}

// ---------------- hyper GEMM: z[2048,1024] = [x|mh|hh] @ BT^T; x uses hi+lo ----------------
__global__ __launch_bounds__(256) void gemm_hyper(const u16* __restrict__ xh,
                                                  const u16* __restrict__ xl,
                                                  const u16* __restrict__ mh,
                                                  const u16* __restrict__ hh,
                                                  const u16* __restrict__ BT,
                                                  float* __restrict__ z) {
    __shared__ __align__(16) u16 sA[64 * 32], sAl[64 * 32], sB[64 * 32];
    int tid = threadIdx.x, lane = tid & 63, wave = tid >> 6;
    int wm = (wave >> 1) * 32, wn = (wave & 1) * 32;
    int bm = blockIdx.y * 64, bn = blockIdx.x * 64;
    floatx4 acc[2][2] = {};
    int mrow = lane & 15, kcol = (lane >> 4) * 8;
    int r = tid >> 2, c8 = tid & 3;
    for (int ph = 0; ph < 3; ph++) {
        const u16* Ap = (ph == 0) ? xh : (ph == 1) ? mh : hh;
        int lda = (ph == 2) ? 256 : 1024;
        int K = (ph == 2) ? 256 : 1024;
        int koff = ph * 1024;
        for (int k0 = 0; k0 < K; k0 += 32) {
            ((bf16x8*)sA)[tid] = *(const bf16x8*)(Ap + (size_t)(bm + r) * lda + k0 + c8 * 8);
            if (ph == 0)
                ((bf16x8*)sAl)[tid] = *(const bf16x8*)(xl + (size_t)(bm + r) * 1024 + k0 + c8 * 8);
            ((bf16x8*)sB)[tid] = *(const bf16x8*)(BT + (size_t)(bn + r) * 2304 + koff + k0 + c8 * 8);
            __syncthreads();
            bf16x8 af[2], afl[2], bfr[2];
            #pragma unroll
            for (int t = 0; t < 2; t++) {
                af[t]  = *(const bf16x8*)&sA[(wm + t * 16 + mrow) * 32 + kcol];
                bfr[t] = *(const bf16x8*)&sB[(wn + t * 16 + mrow) * 32 + kcol];
                if (ph == 0) afl[t] = *(const bf16x8*)&sAl[(wm + t * 16 + mrow) * 32 + kcol];
            }
            #pragma unroll
            for (int tm = 0; tm < 2; tm++)
                #pragma unroll
                for (int tn = 0; tn < 2; tn++) {
                    acc[tm][tn] = __builtin_amdgcn_mfma_f32_16x16x32_bf16(af[tm], bfr[tn], acc[tm][tn], 0, 0, 0);
                    if (ph == 0)
                        acc[tm][tn] = __builtin_amdgcn_mfma_f32_16x16x32_bf16(afl[tm], bfr[tn], acc[tm][tn], 0, 0, 0);
                }
            __syncthreads();
        }
    }
    #pragma unroll
    for (int tm = 0; tm < 2; tm++)
        #pragma unroll
        for (int tn = 0; tn < 2; tn++) {
            int col = bn + wn + tn * 16 + (lane & 15);
            #pragma unroll
            for (int rr = 0; rr < 4; rr++) {
                int row = bm + wm + tm * 16 + (lane >> 4) * 4 + rr;
                z[(size_t)row * 1024 + col] = acc[tm][tn][rr];
            }
        }
}

// ---------------- hyper LSTM cell; hyper_out -> bf16 hi + lo residual ----------------
__global__ void hyper_cell(const float* __restrict__ z, const void* __restrict__ hyper_c,
                           const void* __restrict__ hyper_bias, void* __restrict__ out,
                           u16* __restrict__ ho_hi, u16* __restrict__ ho_lo,
                           const int* __restrict__ flag) {
    int isbf = *flag;
    int t = blockIdx.x * 256 + threadIdx.x;  // 2048*256
    int b = t >> 8, k = t & 255;
    const float* zr = z + (size_t)b * 1024;
    float hi = zr[k]       + ldmix(hyper_bias, k, isbf);
    float hf = zr[k + 256] + ldmix(hyper_bias, k + 256, isbf);
    float hg = zr[k + 512] + ldmix(hyper_bias, k + 512, isbf);
    float ho = zr[k + 768] + ldmix(hyper_bias, k + 768, isbf);
    float c  = ldmix(hyper_c, t, isbf);
    float cn = sigf(hf) * c + sigf(hi) * tanhf(hg);
    float hout = sigf(ho) * tanhf(cn);
    u16 hu = f2bf(hout);
    ho_hi[t] = hu;
    ho_lo[t] = f2bf(hout - bf2f(hu));
    if (isbf) {
        ((u16*)out)[O_HO + t] = hu;
        ((u16*)out)[O_HC + t] = f2bf(cn);
    } else {
        ((float*)out)[O_HO + t] = hout;
        ((float*)out)[O_HC + t] = cn;
    }
}

// ---------------- fused gates GEMM, split-bf16 precision -> gates_pre hi/lo planes ----------------
__global__ __launch_bounds__(256) void mega_gates(
    const u16* __restrict__ xh, const u16* __restrict__ xl, const u16* __restrict__ mh,
    const u16* __restrict__ ho_hi, const u16* __restrict__ ho_lo,
    const u16* __restrict__ kT, const u16* __restrict__ rkT,
    const u16* __restrict__ dxh, const u16* __restrict__ dxl,
    const u16* __restrict__ dhh, const u16* __restrict__ dhl,
    const u16* __restrict__ dbh, const u16* __restrict__ dbl,
    const void* __restrict__ bias, const void* __restrict__ dx_b,
    const void* __restrict__ dh_b, const void* __restrict__ db_b,
    u16* __restrict__ gp_hi, u16* __restrict__ gp_lo, const int* __restrict__ flag) {
    __shared__ __align__(16) u16 sT[8][64 * 32];  // 32 KB
    int isbf = *flag;
    int tid = threadIdx.x, lane = tid & 63, wave = tid >> 6;
    int wm = (wave >> 1) * 32, wn = (wave & 1) * 32;
    int bm = blockIdx.y * 64, bn = blockIdx.x * 64;
    floatx4 apx[2][2] = {}, aph[2][2] = {}, adx[2][2] = {}, adh[2][2] = {}, adb[2][2] = {};
    int mrow = lane & 15, kcol = (lane >> 4) * 8;
    int r = tid >> 2, c8 = tid & 3;

    // phase 1: K=1024; proj_x = (x_hi + x_lo) @ kT, proj_h = mh @ rkT
    for (int k0 = 0; k0 < 1024; k0 += 32) {
        ((bf16x8*)sT[0])[tid] = *(const bf16x8*)(xh  + (size_t)(bm + r) * 1024 + k0 + c8 * 8);
        ((bf16x8*)sT[1])[tid] = *(const bf16x8*)(xl  + (size_t)(bm + r) * 1024 + k0 + c8 * 8);
        ((bf16x8*)sT[2])[tid] = *(const bf16x8*)(mh  + (size_t)(bm + r) * 1024 + k0 + c8 * 8);
        ((bf16x8*)sT[3])[tid] = *(const bf16x8*)(kT  + (size_t)(bn + r) * 1024 + k0 + c8 * 8);
        ((bf16x8*)sT[4])[tid] = *(const bf16x8*)(rkT + (size_t)(bn + r) * 1024 + k0 + c8 * 8);
        __syncthreads();
        bf16x8 axh[2], axl[2], am[2], bk[2], br[2];
        #pragma unroll
        for (int t = 0; t < 2; t++) {
            int ra = (wm + t * 16 + mrow) * 32 + kcol;
            int rb = (wn + t * 16 + mrow) * 32 + kcol;
            axh[t] = *(const bf16x8*)&sT[0][ra];
            axl[t] = *(const bf16x8*)&sT[1][ra];
            am[t]  = *(const bf16x8*)&sT[2][ra];
            bk[t]  = *(const bf16x8*)&sT[3][rb];
            br[t]  = *(const bf16x8*)&sT[4][rb];
        }
        #pragma unroll
        for (int tm = 0; tm < 2; tm++)
            #pragma unroll
            for (int tn = 0; tn < 2; tn++) {
                apx[tm][tn] = __builtin_amdgcn_mfma_f32_16x16x32_bf16(axh[tm], bk[tn], apx[tm][tn], 0, 0, 0);
                apx[tm][tn] = __builtin_amdgcn_mfma_f32_16x16x32_bf16(axl[tm], bk[tn], apx[tm][tn], 0, 0, 0);
                aph[tm][tn] = __builtin_amdgcn_mfma_f32_16x16x32_bf16(am[tm],  br[tn], aph[tm][tn], 0, 0, 0);
            }
        __syncthreads();
    }
    // phase 2: K=256; d_* = (ho_hi + ho_lo) @ (W_hi + W_lo), lo*lo dropped
    for (int k0 = 0; k0 < 256; k0 += 32) {
        ((bf16x8*)sT[0])[tid] = *(const bf16x8*)(ho_hi + (size_t)(bm + r) * 256 + k0 + c8 * 8);
        ((bf16x8*)sT[1])[tid] = *(const bf16x8*)(ho_lo + (size_t)(bm + r) * 256 + k0 + c8 * 8);
        ((bf16x8*)sT[2])[tid] = *(const bf16x8*)(dxh + (size_t)(bn + r) * 256 + k0 + c8 * 8);
        ((bf16x8*)sT[3])[tid] = *(const bf16x8*)(dxl + (size_t)(bn + r) * 256 + k0 + c8 * 8);
        ((bf16x8*)sT[4])[tid] = *(const bf16x8*)(dhh + (size_t)(bn + r) * 256 + k0 + c8 * 8);
        ((bf16x8*)sT[5])[tid] = *(const bf16x8*)(dhl + (size_t)(bn + r) * 256 + k0 + c8 * 8);
        ((bf16x8*)sT[6])[tid] = *(const bf16x8*)(dbh + (size_t)(bn + r) * 256 + k0 + c8 * 8);
        ((bf16x8*)sT[7])[tid] = *(const bf16x8*)(dbl + (size_t)(bn + r) * 256 + k0 + c8 * 8);
        __syncthreads();
        bf16x8 a[2], al[2], bxh[2], bxl[2], bhh[2], bhl[2], bbh[2], bbl[2];
        #pragma unroll
        for (int t = 0; t < 2; t++) {
            int ra = (wm + t * 16 + mrow) * 32 + kcol;
            int rb = (wn + t * 16 + mrow) * 32 + kcol;
            a[t]   = *(const bf16x8*)&sT[0][ra];
            al[t]  = *(const bf16x8*)&sT[1][ra];
            bxh[t] = *(const bf16x8*)&sT[2][rb];
            bxl[t] = *(const bf16x8*)&sT[3][rb];
            bhh[t] = *(const bf16x8*)&sT[4][rb];
            bhl[t] = *(const bf16x8*)&sT[5][rb];
            bbh[t] = *(const bf16x8*)&sT[6][rb];
            bbl[t] = *(const bf16x8*)&sT[7][rb];
        }
        #pragma unroll
        for (int tm = 0; tm < 2; tm++)
            #pragma unroll
            for (int tn = 0; tn < 2; tn++) {
                adx[tm][tn] = __builtin_amdgcn_mfma_f32_16x16x32_bf16(a[tm],  bxh[tn], adx[tm][tn], 0, 0, 0);
                adx[tm][tn] = __builtin_amdgcn_mfma_f32_16x16x32_bf16(al[tm], bxh[tn], adx[tm][tn], 0, 0, 0);
                adx[tm][tn] = __builtin_amdgcn_mfma_f32_16x16x32_bf16(a[tm],  bxl[tn], adx[tm][tn], 0, 0, 0);
                adh[tm][tn] = __builtin_amdgcn_mfma_f32_16x16x32_bf16(a[tm],  bhh[tn], adh[tm][tn], 0, 0, 0);
                adh[tm][tn] = __builtin_amdgcn_mfma_f32_16x16x32_bf16(al[tm], bhh[tn], adh[tm][tn], 0, 0, 0);
                adh[tm][tn] = __builtin_amdgcn_mfma_f32_16x16x32_bf16(a[tm],  bhl[tn], adh[tm][tn], 0, 0, 0);
                adb[tm][tn] = __builtin_amdgcn_mfma_f32_16x16x32_bf16(a[tm],  bbh[tn], adb[tm][tn], 0, 0, 0);
                adb[tm][tn] = __builtin_amdgcn_mfma_f32_16x16x32_bf16(al[tm], bbh[tn], adb[tm][tn], 0, 0, 0);
                adb[tm][tn] = __builtin_amdgcn_mfma_f32_16x16x32_bf16(a[tm],  bbl[tn], adb[tm][tn], 0, 0, 0);
            }
        __syncthreads();
    }
    // epilogue
    #pragma unroll
    for (int tm = 0; tm < 2; tm++)
        #pragma unroll
        for (int tn = 0; tn < 2; tn++) {
            int col = bn + wn + tn * 16 + (lane & 15);
            float bv  = ldmix(bias, col, isbf);
            float dxb = ldmix(dx_b, col, isbf);
            float dhb = ldmix(dh_b, col, isbf);
            float dbb = ldmix(db_b, col, isbf);
            #pragma unroll
            for (int rr = 0; rr < 4; rr++) {
                int row = bm + wm + tm * 16 + (lane >> 4) * 4 + rr;
                float px = apx[tm][tn][rr] + bv;
                float ph = aph[tm][tn][rr];
                float dx = adx[tm][tn][rr] + dxb;
                float dh = adh[tm][tn][rr] + dhb;
                float db = adb[tm][tn][rr] + dbb;
                float g = dx * px + dh * ph + db;
                u16 hi = f2bf(g);
                gp_hi[(size_t)row * 4096 + col] = hi;
                gp_lo[(size_t)row * 4096 + col] = f2bf(g - bf2f(hi));
            }
        }
}

// ---------------- LN(4096) -> gates -> c_new -> LN(1024) -> h_new ----------------
__device__ __forceinline__ void block_reduce2(float& a, float& b, float* red) {
    #pragma unroll
    for (int o = 32; o > 0; o >>= 1) {
        a += __shfl_down(a, o, 64);
        b += __shfl_down(b, o, 64);
    }
    int lane = threadIdx.x & 63, w = threadIdx.x >> 6;
    if (lane == 0) { red[w] = a; red[4 + w] = b; }
    __syncthreads();
    a = red[0] + red[1] + red[2] + red[3];
    b = red[4] + red[5] + red[6] + red[7];
    __syncthreads();
}

__global__ __launch_bounds__(256) void ln_main(const u16* __restrict__ gp_hi,
                                               const u16* __restrict__ gp_lo,
                                               const void* __restrict__ main_c,
                                               void* __restrict__ out,
                                               const int* __restrict__ flag) {
    __shared__ float sPre[4096];
    __shared__ float sC[1024];
    __shared__ float red[8];
    int isbf = *flag;
    int b = blockIdx.x, tid = threadIdx.x;
    const u16* gh = gp_hi + (size_t)b * 4096;
    const u16* gl = gp_lo + (size_t)b * 4096;
    float s = 0.f, q = 0.f;
    for (int j = tid; j < 4096; j += 256) {
        float v = bf2f(gh[j]) + bf2f(gl[j]);
        sPre[j] = v; s += v; q += v * v;
    }
    block_reduce2(s, q, red);
    float mean = s * (1.f / 4096.f);
    float var = q * (1.f / 4096.f) - mean * mean;
    float rs = rsqrtf(var + 1e-3f);
    float s2 = 0.f, q2 = 0.f;
    for (int u = tid; u < 1024; u += 256) {
        float gi = (sPre[u] - mean) * rs;
        float gf = (sPre[u + 1024] - mean) * rs;
        float gg = (sPre[u + 2048] - mean) * rs;
        float c = ldmix(main_c, (size_t)b * 1024 + u, isbf);
        float cn = sigf(gf) * c + sigf(gi) * tanhf(gg);
        sC[u] = cn;
        if (isbf) ((u16*)out)[O_C + (size_t)b * 1024 + u] = f2bf(cn);
        else      ((float*)out)[O_C + (size_t)b * 1024 + u] = cn;
        s2 += cn; q2 += cn * cn;
    }
    block_reduce2(s2, q2, red);
    float m2 = s2 * (1.f / 1024.f);
    float v2 = q2 * (1.f / 1024.f) - m2 * m2;
    float rs2 = rsqrtf(v2 + 1e-3f);
    for (int u = tid; u < 1024; u += 256) {
        float go = (sPre[u + 3072] - mean) * rs;
        float hn = sigf(go) * tanhf((sC[u] - m2) * rs2);
        if (isbf) ((u16*)out)[O_H + (size_t)b * 1024 + u] = f2bf(hn);
        else      ((float*)out)[O_H + (size_t)b * 1024 + u] = hn;
    }
}

// ---------------- launcher ----------------
extern "C" void kernel_launch(void* const* d_in, const int* in_sizes, int n_in,
                              void* d_out, int out_size, void* d_ws, size_t ws_size,
                              hipStream_t stream) {
    (void)in_sizes; (void)n_in; (void)out_size; (void)ws_size;
    const void* inputs   = d_in[0];
    const void* main_h   = d_in[1];
    const void* main_c   = d_in[2];
    const void* hyper_h  = d_in[3];
    const void* hyper_c  = d_in[4];
    const void* kernel_w = d_in[5];
    const void* rec_w    = d_in[6];
    const void* bias     = d_in[7];
    const void* hyper_k  = d_in[8];
    const void* hyper_rk = d_in[9];
    const void* hyper_b  = d_in[10];
    const void* dx_w = d_in[11];
    const void* dx_b = d_in[12];
    const void* dh_w = d_in[13];
    const void* dh_b = d_in[14];
    const void* db_w = d_in[15];
    const void* db_b = d_in[16];
    char* ws = (char*)d_ws;

    // workspace layout (bytes); total ~59.3 MB
    int* flag = (int*)ws;
    size_t off = 256;
    u16* xinh = (u16*)(ws + off); off += (size_t)2048 * 1024 * 2;  // 4 MB
    u16* xinl = (u16*)(ws + off); off += (size_t)2048 * 1024 * 2;  // 4 MB
    u16* mh   = (u16*)(ws + off); off += (size_t)2048 * 1024 * 2;  // 4 MB
    u16* hh   = (u16*)(ws + off); off += (size_t)2048 * 256 * 2;   // 1 MB
    u16* hohi = (u16*)(ws + off); off += (size_t)2048 * 256 * 2;   // 1 MB
    u16* holo = (u16*)(ws + off); off += (size_t)2048 * 256 * 2;   // 1 MB
    u16* kT   = (u16*)(ws + off); off += (size_t)4096 * 1024 * 2;  // 8 MB
    u16* rkT  = (u16*)(ws + off); off += (size_t)4096 * 1024 * 2;  // 8 MB
    u16* dxh  = (u16*)(ws + off); off += (size_t)4096 * 256 * 2;   // 2 MB
    u16* dxl  = (u16*)(ws + off); off += (size_t)4096 * 256 * 2;   // 2 MB
    u16* dhh  = (u16*)(ws + off); off += (size_t)4096 * 256 * 2;   // 2 MB
    u16* dhl  = (u16*)(ws + off); off += (size_t)4096 * 256 * 2;   // 2 MB
    u16* dbh  = (u16*)(ws + off); off += (size_t)4096 * 256 * 2;   // 2 MB
    u16* dbl  = (u16*)(ws + off); off += (size_t)4096 * 256 * 2;   // 2 MB
    char* region = ws + off;  // 16 MB region, double-used
    u16* BTh = (u16*)region;                                   // [1024,2304] 4.5 MB
    float* zbuf = (float*)(region + (size_t)1024 * 2304 * 2);  // [2048,1024] 8 MB
    u16* gphi = (u16*)region;                                  // [2048,4096] 8 MB (after hyper phase)
    u16* gplo = (u16*)(region + (size_t)2048 * 4096 * 2);      // 8 MB

    detect_dtype<<<1, 64, 0, stream>>>((const u16*)inputs, flag);

    cvt_in2<<<1024, 256, 0, stream>>>(inputs, xinh, xinl, 262144, flag);
    cvt_in2<<<1024, 256, 0, stream>>>(main_h, mh, nullptr, 262144, flag);
    cvt_in2<<<256, 256, 0, stream>>>(hyper_h, hh, nullptr, 65536, flag);

    dim3 tblk(32, 8);
    transpose_cvt2<<<dim3(32, 64), tblk, 0, stream>>>(hyper_k, BTh, nullptr, 2048, 1024, 2304, 0, flag);
    transpose_cvt2<<<dim3(32, 8),  tblk, 0, stream>>>(hyper_rk, BTh, nullptr, 256, 1024, 2304, 2048, flag);
    transpose_cvt2<<<dim3(128, 32), tblk, 0, stream>>>(kernel_w, kT, nullptr, 1024, 4096, 1024, 0, flag);
    transpose_cvt2<<<dim3(128, 32), tblk, 0, stream>>>(rec_w, rkT, nullptr, 1024, 4096, 1024, 0, flag);
    transpose_cvt2<<<dim3(128, 8),  tblk, 0, stream>>>(dx_w, dxh, dxl, 256, 4096, 256, 0, flag);
    transpose_cvt2<<<dim3(128, 8),  tblk, 0, stream>>>(dh_w, dhh, dhl, 256, 4096, 256, 0, flag);
    transpose_cvt2<<<dim3(128, 8),  tblk, 0, stream>>>(db_w, dbh, dbl, 256, 4096, 256, 0, flag);

    gemm_hyper<<<dim3(16, 32), 256, 0, stream>>>(xinh, xinl, mh, hh, BTh, zbuf);
    hyper_cell<<<2048, 256, 0, stream>>>(zbuf, hyper_c, hyper_b, d_out, hohi, holo, flag);
    // BTh/zbuf dead from here; gphi/gplo overwrite the region
    mega_gates<<<dim3(64, 32), 256, 0, stream>>>(xinh, xinl, mh, hohi, holo, kT, rkT,
                                                 dxh, dxl, dhh, dhl, dbh, dbl,
                                                 bias, dx_b, dh_b, db_b, gphi, gplo, flag);
    ln_main<<<2048, 256, 0, stream>>>(gphi, gplo, main_c, d_out, flag);
}